// Round 1
// baseline (84.128 us; speedup 1.0000x reference)
//
#include <hip/hip_runtime.h>

// ChamferLoss: B=4, C=3, N=M=8192 fp32.
// loss = 2 * mean_b( sum_n min_m ||pos1[b,n] - pos2[b,m]||^2 ), clamped >= 0.
// pos1 = pc2 (queries), pos2 = pc1_warped (refs), both stored [B, C, N] planar.
//
// Rewrite: d = q2 + r2 - 2*dot. Track smax = max_m (dot - 0.5*r2);
// d_min = max(q2 - 2*smax, 0). Inner loop = 3 FMA + 1 max per pair.

#define NPTS    8192
#define NB      4
#define TOTQ    (NB * NPTS)   // 32768
#define BQ      256           // threads per block (kernel 1)
#define QT      4             // queries per thread
#define QPB     (BQ * QT)     // 1024 queries per block
#define MC      512           // ref points per m-chunk
#define MCHUNKS (NPTS / MC)   // 16

__global__ __launch_bounds__(BQ) void chamfer_partial(
    const float* __restrict__ pc2,       // queries [B,3,N]
    const float* __restrict__ pc1w,      // refs    [B,3,N]
    float* __restrict__ partial)         // [MCHUNKS, TOTQ] smax partials
{
    __shared__ float4 lds[MC];           // (rx, ry, rz, -0.5*r2)
    const int tid = threadIdx.x;
    const int b  = blockIdx.z;
    const int m0 = blockIdx.y * MC;
    const int q0 = blockIdx.x * QPB;

    const float* refb = pc1w + b * 3 * NPTS;
    for (int i = tid; i < MC; i += BQ) {
        float rx = refb[m0 + i];
        float ry = refb[NPTS + m0 + i];
        float rz = refb[2 * NPTS + m0 + i];
        float h  = -0.5f * (rx * rx + ry * ry + rz * rz);
        lds[i] = make_float4(rx, ry, rz, h);
    }
    __syncthreads();

    const float* qb = pc2 + b * 3 * NPTS;
    float qx[QT], qy[QT], qz[QT], smax[QT];
#pragma unroll
    for (int j = 0; j < QT; ++j) {
        int q = q0 + tid + j * BQ;
        qx[j] = qb[q];
        qy[j] = qb[NPTS + q];
        qz[j] = qb[2 * NPTS + q];
        smax[j] = -1e30f;
    }

#pragma unroll 4
    for (int m = 0; m < MC; ++m) {
        float4 r = lds[m];
#pragma unroll
        for (int j = 0; j < QT; ++j) {
            float s = fmaf(qx[j], r.x, r.w);
            s = fmaf(qy[j], r.y, s);
            s = fmaf(qz[j], r.z, s);
            smax[j] = fmaxf(smax[j], s);
        }
    }

#pragma unroll
    for (int j = 0; j < QT; ++j) {
        int q = q0 + tid + j * BQ;
        partial[blockIdx.y * TOTQ + b * NPTS + q] = smax[j];
    }
}

__global__ __launch_bounds__(256) void chamfer_reduce(
    const float* __restrict__ pc2,
    const float* __restrict__ partial,
    float* __restrict__ out)
{
    const int g = blockIdx.x * blockDim.x + threadIdx.x;  // query id 0..TOTQ-1
    float smax = -1e30f;
#pragma unroll
    for (int c = 0; c < MCHUNKS; ++c)
        smax = fmaxf(smax, partial[c * TOTQ + g]);

    const int b = g / NPTS;
    const int n = g & (NPTS - 1);
    const float* qb = pc2 + b * 3 * NPTS;
    float qx = qb[n], qy = qb[NPTS + n], qz = qb[2 * NPTS + n];
    float q2 = qx * qx + qy * qy + qz * qz;
    float d = fmaxf(q2 - 2.0f * smax, 0.0f);

    // wave-64 reduction
#pragma unroll
    for (int off = 32; off > 0; off >>= 1)
        d += __shfl_down(d, off, 64);

    __shared__ float wsum[4];
    const int lane = threadIdx.x & 63;
    const int wid  = threadIdx.x >> 6;
    if (lane == 0) wsum[wid] = d;
    __syncthreads();
    if (threadIdx.x == 0) {
        float s = wsum[0] + wsum[1] + wsum[2] + wsum[3];
        atomicAdd(out, s * (2.0f / NB));   // 2 * mean over batches
    }
}

extern "C" void kernel_launch(void* const* d_in, const int* in_sizes, int n_in,
                              void* d_out, int out_size, void* d_ws, size_t ws_size,
                              hipStream_t stream) {
    const float* pc2  = (const float*)d_in[0];
    const float* pc1w = (const float*)d_in[1];
    float* out = (float*)d_out;
    float* partial = (float*)d_ws;   // MCHUNKS * TOTQ * 4 B = 2 MiB

    dim3 g1(NPTS / QPB, MCHUNKS, NB);   // (8, 16, 4) = 512 blocks
    chamfer_partial<<<g1, BQ, 0, stream>>>(pc2, pc1w, partial);

    hipMemsetAsync(out, 0, sizeof(float), stream);
    chamfer_reduce<<<TOTQ / 256, 256, 0, stream>>>(pc2, partial, out);
}

// Round 2
// 81.340 us; speedup vs baseline: 1.0343x; 1.0343x over previous
//
#include <hip/hip_runtime.h>

// ChamferLoss: B=4, C=3, N=M=8192 fp32.
// loss = 2 * mean_b( sum_n min_m ||pos1[b,n] - pos2[b,m]||^2 ), clamped >= 0.
// Rewrite: d = q2 + r2 - 2*dot. Track smax = max_m (dot - 0.5*r2);
// d_min = max(q2 - 2*smax, 0).
// Packed fp32 (v_pk_fma_f32): 2 queries per lane-slot -> 2.5 inst/pair.

#define NPTS    8192
#define NB      4
#define TOTQ    (NB * NPTS)   // 32768
#define BQ      256           // threads per block (kernel 1)
#define QV      4             // float2 groups per thread -> 8 queries/thread
#define QPB     (BQ * QV * 2) // 2048 queries per block
#define MC      256           // ref points per m-chunk
#define MCHUNKS (NPTS / MC)   // 32

typedef float v2f __attribute__((ext_vector_type(2)));

#if __has_builtin(__builtin_elementwise_fma)
#define VFMA(a, b, c) __builtin_elementwise_fma((a), (b), (c))
#else
#define VFMA(a, b, c) ((a) * (b) + (c))
#endif
#if __has_builtin(__builtin_elementwise_max)
#define VMAX(a, b) __builtin_elementwise_max((a), (b))
#else
static __device__ inline v2f VMAX(v2f a, v2f b) {
    v2f r; r.x = fmaxf(a.x, b.x); r.y = fmaxf(a.y, b.y); return r;
}
#endif

__global__ __launch_bounds__(BQ) void chamfer_partial(
    const float* __restrict__ pc2,       // queries [B,3,N]
    const float* __restrict__ pc1w,      // refs    [B,3,N]
    float* __restrict__ partial)         // [MCHUNKS, TOTQ] smax partials
{
    __shared__ float4 lds[MC];           // (rx, ry, rz, -0.5*r2)
    const int tid = threadIdx.x;
    const int b  = blockIdx.z;
    const int m0 = blockIdx.y * MC;
    const int q0 = blockIdx.x * QPB;

    const float* refb = pc1w + b * 3 * NPTS;
    if (tid < MC) {
        int i = tid;
        float rx = refb[m0 + i];
        float ry = refb[NPTS + m0 + i];
        float rz = refb[2 * NPTS + m0 + i];
        float h  = -0.5f * (rx * rx + ry * ry + rz * rz);
        lds[i] = make_float4(rx, ry, rz, h);
    }
    __syncthreads();

    const float* qb = pc2 + b * 3 * NPTS;
    v2f qx[QV], qy[QV], qz[QV], smax[QV];
#pragma unroll
    for (int j = 0; j < QV; ++j) {
        int off = q0 + j * 2 * BQ;                    // 8B-aligned base
        qx[j] = ((const v2f*)(qb + off))[tid];
        qy[j] = ((const v2f*)(qb + NPTS + off))[tid];
        qz[j] = ((const v2f*)(qb + 2 * NPTS + off))[tid];
        smax[j] = (v2f){-1e30f, -1e30f};
    }

#pragma unroll 4
    for (int m = 0; m < MC; ++m) {
        float4 r = lds[m];
        v2f rx = {r.x, r.x}, ry = {r.y, r.y}, rz = {r.z, r.z}, rw = {r.w, r.w};
#pragma unroll
        for (int j = 0; j < QV; ++j) {
            v2f s = VFMA(qx[j], rx, rw);
            s = VFMA(qy[j], ry, s);
            s = VFMA(qz[j], rz, s);
            smax[j] = VMAX(smax[j], s);
        }
    }

    float* pbase = partial + blockIdx.y * TOTQ + b * NPTS;
#pragma unroll
    for (int j = 0; j < QV; ++j) {
        int off = q0 + j * 2 * BQ;
        ((v2f*)(pbase + off))[tid] = smax[j];
    }
}

__global__ __launch_bounds__(256) void chamfer_reduce(
    const float* __restrict__ pc2,
    const float* __restrict__ partial,
    float* __restrict__ out)
{
    const int g = blockIdx.x * blockDim.x + threadIdx.x;  // query id 0..TOTQ-1
    float smax = -1e30f;
#pragma unroll
    for (int c = 0; c < MCHUNKS; ++c)
        smax = fmaxf(smax, partial[c * TOTQ + g]);

    const int b = g / NPTS;
    const int n = g & (NPTS - 1);
    const float* qb = pc2 + b * 3 * NPTS;
    float qx = qb[n], qy = qb[NPTS + n], qz = qb[2 * NPTS + n];
    float q2 = qx * qx + qy * qy + qz * qz;
    float d = fmaxf(q2 - 2.0f * smax, 0.0f);

    // wave-64 reduction
#pragma unroll
    for (int off = 32; off > 0; off >>= 1)
        d += __shfl_down(d, off, 64);

    __shared__ float wsum[4];
    const int lane = threadIdx.x & 63;
    const int wid  = threadIdx.x >> 6;
    if (lane == 0) wsum[wid] = d;
    __syncthreads();
    if (threadIdx.x == 0) {
        float s = wsum[0] + wsum[1] + wsum[2] + wsum[3];
        atomicAdd(out, s * (2.0f / NB));   // 2 * mean over batches
    }
}

extern "C" void kernel_launch(void* const* d_in, const int* in_sizes, int n_in,
                              void* d_out, int out_size, void* d_ws, size_t ws_size,
                              hipStream_t stream) {
    const float* pc2  = (const float*)d_in[0];
    const float* pc1w = (const float*)d_in[1];
    float* out = (float*)d_out;
    float* partial = (float*)d_ws;   // MCHUNKS * TOTQ * 4 B = 4 MiB

    dim3 g1(NPTS / QPB, MCHUNKS, NB);   // (4, 32, 4) = 512 blocks
    chamfer_partial<<<g1, BQ, 0, stream>>>(pc2, pc1w, partial);

    hipMemsetAsync(out, 0, sizeof(float), stream);
    chamfer_reduce<<<TOTQ / 256, 256, 0, stream>>>(pc2, partial, out);
}

// Round 3
// 80.126 us; speedup vs baseline: 1.0499x; 1.0151x over previous
//
#include <hip/hip_runtime.h>

// ChamferLoss: B=4, C=3, N=M=8192 fp32.
// loss = 2 * mean_b( sum_n min_m ||pos1[b,n] - pos2[b,m]||^2 ), clamped >= 0.
// Rewrite: d = q2 + r2 - 2*dot. Track smax = max_m (dot - 0.5*r2);
// d_min = max(q2 - 2*smax, 0).
// Inner loop: refs packed in pairs -> 3 v_pk_fma_f32 + 1 v_max3_f32
// per (query, ref-pair) = 2.0 inst/pair.

#define NPTS    8192
#define NB      4
#define TOTQ    (NB * NPTS)   // 32768
#define BQ      256           // threads per block (kernel 1)
#define QT      8             // queries per thread
#define QPB     (BQ * QT)     // 2048 queries per block
#define MC      256           // refs per m-chunk
#define MP      (MC / 2)      // 128 ref pairs
#define MCHUNKS (NPTS / MC)   // 32

typedef float v2f __attribute__((ext_vector_type(2)));

#if __has_builtin(__builtin_elementwise_fma)
#define VFMA(a, b, c) __builtin_elementwise_fma((a), (b), (c))
#else
#define VFMA(a, b, c) ((a) * (b) + (c))
#endif

__global__ __launch_bounds__(BQ) void chamfer_partial(
    const float* __restrict__ pc2,       // queries [B,3,N]
    const float* __restrict__ pc1w,      // refs    [B,3,N]
    float* __restrict__ partial,         // [MCHUNKS, TOTQ] smax partials
    float* __restrict__ out)             // zeroed here for K2's atomics
{
    // per ref-pair: {x0,x1},{y0,y1},{z0,z1},{h0,h1} -> 32 B, 16B-aligned
    __shared__ v2f lds[MP * 4];
    const int tid = threadIdx.x;
    const int b  = blockIdx.z;
    const int m0 = blockIdx.y * MC;
    const int q0 = blockIdx.x * QPB;

    if (blockIdx.x == 0 && blockIdx.y == 0 && blockIdx.z == 0 && tid == 0)
        out[0] = 0.0f;   // K2 accumulates; stream order makes this safe

    const float* refb = pc1w + b * 3 * NPTS;
    {
        int i = tid;                     // 256 threads stage 256 refs
        float rx = refb[m0 + i];
        float ry = refb[NPTS + m0 + i];
        float rz = refb[2 * NPTS + m0 + i];
        float h  = -0.5f * (rx * rx + ry * ry + rz * rz);
        float* lf = (float*)lds;
        int base = (i >> 1) * 8 + (i & 1);
        lf[base + 0] = rx;
        lf[base + 2] = ry;
        lf[base + 4] = rz;
        lf[base + 6] = h;
    }
    __syncthreads();

    const float* qb = pc2 + b * 3 * NPTS;
    v2f qx2[QT], qy2[QT], qz2[QT];
    float smax[QT];
#pragma unroll
    for (int g4 = 0; g4 < 2; ++g4) {     // 2 float4 groups -> 8 queries
        int off = q0 + g4 * (BQ * 4);
        float4 fx = ((const float4*)(qb + off))[tid];
        float4 fy = ((const float4*)(qb + NPTS + off))[tid];
        float4 fz = ((const float4*)(qb + 2 * NPTS + off))[tid];
        int j = g4 * 4;
        qx2[j+0] = (v2f){fx.x, fx.x}; qx2[j+1] = (v2f){fx.y, fx.y};
        qx2[j+2] = (v2f){fx.z, fx.z}; qx2[j+3] = (v2f){fx.w, fx.w};
        qy2[j+0] = (v2f){fy.x, fy.x}; qy2[j+1] = (v2f){fy.y, fy.y};
        qy2[j+2] = (v2f){fy.z, fy.z}; qy2[j+3] = (v2f){fy.w, fy.w};
        qz2[j+0] = (v2f){fz.x, fz.x}; qz2[j+1] = (v2f){fz.y, fz.y};
        qz2[j+2] = (v2f){fz.z, fz.z}; qz2[j+3] = (v2f){fz.w, fz.w};
    }
#pragma unroll
    for (int j = 0; j < QT; ++j) smax[j] = -1e30f;

#pragma unroll 2
    for (int p = 0; p < MP; ++p) {
        v2f rx = lds[p * 4 + 0];
        v2f ry = lds[p * 4 + 1];
        v2f rz = lds[p * 4 + 2];
        v2f rh = lds[p * 4 + 3];
#pragma unroll
        for (int j = 0; j < QT; ++j) {
            v2f s = VFMA(qx2[j], rx, rh);
            s = VFMA(qy2[j], ry, s);
            s = VFMA(qz2[j], rz, s);
            smax[j] = fmaxf(smax[j], fmaxf(s[0], s[1]));  // v_max3_f32
        }
    }

    float* pbase = partial + blockIdx.y * TOTQ + b * NPTS;
#pragma unroll
    for (int g4 = 0; g4 < 2; ++g4) {
        int off = q0 + g4 * (BQ * 4);
        int j = g4 * 4;
        float4 o = make_float4(smax[j], smax[j+1], smax[j+2], smax[j+3]);
        ((float4*)(pbase + off))[tid] = o;
    }
}

__global__ __launch_bounds__(512) void chamfer_reduce(
    const float* __restrict__ pc2,
    const float* __restrict__ partial,
    float* __restrict__ out)
{
    const int g = blockIdx.x * 512 + threadIdx.x;  // query id, 64 blocks
    float smax = -1e30f;
#pragma unroll
    for (int c = 0; c < MCHUNKS; ++c)
        smax = fmaxf(smax, partial[c * TOTQ + g]);

    const int b = g >> 13;          // / NPTS
    const int n = g & (NPTS - 1);
    const float* qb = pc2 + b * 3 * NPTS;
    float qx = qb[n], qy = qb[NPTS + n], qz = qb[2 * NPTS + n];
    float q2 = qx * qx + qy * qy + qz * qz;
    float d = fmaxf(q2 - 2.0f * smax, 0.0f);

    // wave-64 reduction
#pragma unroll
    for (int off = 32; off > 0; off >>= 1)
        d += __shfl_down(d, off, 64);

    __shared__ float wsum[8];
    const int lane = threadIdx.x & 63;
    const int wid  = threadIdx.x >> 6;
    if (lane == 0) wsum[wid] = d;
    __syncthreads();
    if (threadIdx.x == 0) {
        float s = 0.0f;
#pragma unroll
        for (int w = 0; w < 8; ++w) s += wsum[w];
        atomicAdd(out, s * (2.0f / NB));   // 2 * mean over batches
    }
}

extern "C" void kernel_launch(void* const* d_in, const int* in_sizes, int n_in,
                              void* d_out, int out_size, void* d_ws, size_t ws_size,
                              hipStream_t stream) {
    const float* pc2  = (const float*)d_in[0];
    const float* pc1w = (const float*)d_in[1];
    float* out = (float*)d_out;
    float* partial = (float*)d_ws;   // MCHUNKS * TOTQ * 4 B = 4 MiB

    dim3 g1(NPTS / QPB, MCHUNKS, NB);   // (4, 32, 4) = 512 blocks
    chamfer_partial<<<g1, BQ, 0, stream>>>(pc2, pc1w, partial, out);
    chamfer_reduce<<<TOTQ / 512, 512, 0, stream>>>(pc2, partial, out);
}